// Round 13
// baseline (97.994 us; speedup 1.0000x reference)
//
#include <hip/hip_runtime.h>

// out[b,o,i,j] = sum_c | sum_{ti,tj<=8} K[o,0,ti,tj] * x[b,c,(i+5-ti)&127,(j+5-tj)&127] |
// B=8 C=16 H=W=128 O=32.
// R13: single fused launch = R5-verified staging (column-reversed bf16 LDS
//   image, LOAD_SLOT, 2-row halo NROW=11) + R12-verified 32x32x16 compute
//   (chunk = tap-row ti, K=16, 9 chunks, 8 phases via ph-wave split +
//   alignbit extraction) + R12-verified D-map epilogue (stride-129 LDS
//   transpose, cg-reduce, coalesced flush). No prep kernel, no xr round-trip.
//   Staging: 50 slots/thread in two 25-slot register-bounded batches
//   (R4 spill lesson). B-frags computed inline from kern (L1-hot).
//   Spill tell: WRITE_SIZE > 16384 KB. Correctness tell: absmax == 0.0625.

typedef __attribute__((ext_vector_type(8)))  short  short8;
typedef __attribute__((ext_vector_type(16))) float  float16v;
typedef __attribute__((ext_vector_type(4)))  float  float4v;
typedef __attribute__((ext_vector_type(4)))  unsigned int uint4v;

#define NROW 11                  // halo rows for 2 output rows: i0-4 .. i0+6
#define NCC  144                 // bf16 per LDS row = 288 B row stride
#define CHSZ (NROW * NCC)        // 1584 bf16 = 3168 B per channel
#define CHB  3168
#define NSLOT (16 * NROW * 72)   // 12672 dword slots total

__device__ __forceinline__ unsigned int f2bf(float f) {
    union { float f; unsigned int u; } a; a.f = f;
    unsigned int u = a.u;
    u += 0x7fffu + ((u >> 16) & 1u);   // RNE
    return u >> 16;
}

#if __has_builtin(__builtin_amdgcn_alignbit)
#define ALIGN16(hi_, lo_) __builtin_amdgcn_alignbit((hi_), (lo_), 16)
#else
#define ALIGN16(hi_, lo_) \
    (unsigned int)((((unsigned long long)(hi_) << 32) | (lo_)) >> 16)
#endif

#define FRAG_EVEN(q_) __builtin_bit_cast(short8, (uint4v){                    \
        wnd[(q_)+0], wnd[(q_)+1], wnd[(q_)+2], wnd[(q_)+3]})
#define FRAG_ODD(q_)  __builtin_bit_cast(short8, (uint4v){                    \
        ALIGN16(wnd[(q_)+1], wnd[(q_)+0]),                                    \
        ALIGN16(wnd[(q_)+2], wnd[(q_)+1]),                                    \
        ALIGN16(wnd[(q_)+3], wnd[(q_)+2]),                                    \
        ALIGN16(wnd[(q_)+4], wnd[(q_)+3])})

// decode dword slot s -> loads + LDS dword index (R5-verified, 2-row halo)
#define LOAD_SLOT(s_, v0_, v1_, ad_)                                         \
    {                                                                        \
        int ch  = (s_) / 792;                                                \
        int rem = (s_) - 792 * ch;                                           \
        int rr  = rem / 72;                                                  \
        int ccd = rem - 72 * rr;                                             \
        int cc  = 2 * ccd;                                                   \
        int xrow = (i0 - 4 + rr) & 127;                                      \
        const float* xp = xb + (ch << 14) + (xrow << 7);                     \
        v0_ = xp[(132 - cc) & 127];                                          \
        v1_ = xp[(131 - cc) & 127];                                          \
        ad_ = ch * CHSZ + rr * NCC + cc;                                     \
    }

__global__ __launch_bounds__(256, 2)
void optical_conv_69698729279498(const float* __restrict__ x,
                                 const float* __restrict__ kern,
                                 float* __restrict__ out) {
    __shared__ __align__(16) unsigned short ldsb[16 * CHSZ];  // 50688 B

    const int tid = threadIdx.x;
    const int l   = tid & 63;
    const int w   = tid >> 6;        // wave 0..3
    const int ph  = w & 1;           // phase half: p = 4*ph + pp
    const int cg  = w >> 1;          // channel group 0..1
    const int i0  = blockIdx.x * 2;  // first output row of tile
    const int b   = blockIdx.y;      // batch 0..7

    const int jm  = l & 15;          // A m: m = 16*rl + jm
    const int rl  = (l >> 4) & 1;    // row within 2-row tile (per-lane)
    const int hi  = l >> 5;          // k half: tj = 8*hi + j

    const float* xb = x + ((size_t)b << 18);   // batch slice [16,128,128]

    // ---- staging: 50 slots/thread, two register-bounded 25-slot batches
    {
        float v0a[25], v1a[25]; int aa[25];
#pragma unroll
        for (int k = 0; k < 25; ++k) {
            int s = tid + 256 * k;                 // max 6399 < 12672
            LOAD_SLOT(s, v0a[k], v1a[k], aa[k]);
        }
#pragma unroll
        for (int k = 0; k < 25; ++k) {
            unsigned int pk2 = f2bf(v0a[k]) | (f2bf(v1a[k]) << 16);
            *(unsigned int*)&ldsb[aa[k]] = pk2;
        }
#pragma unroll
        for (int k = 0; k < 25; ++k) {
            int s = tid + 256 * (25 + k);
            if (s > NSLOT - 1) s = NSLOT - 1;      // clamped dups: same data
            LOAD_SLOT(s, v0a[k], v1a[k], aa[k]);
        }
#pragma unroll
        for (int k = 0; k < 25; ++k) {
            unsigned int pk2 = f2bf(v0a[k]) | (f2bf(v1a[k]) << 16);
            *(unsigned int*)&ldsb[aa[k]] = pk2;
        }
    }

    // ---- B fragments inline (32x32x16 layout, R12 prep_b logic verbatim):
    //      lane: o = l&31, k = 8*hi + j; Bf[ti][j] = K[o, ti, 8*hi+j] (tj>8 -> 0)
    short8 Bf[9];
    {
        const int o = l & 31;
#pragma unroll
        for (int ti = 0; ti < 9; ++ti) {
            unsigned int pk[4];
#pragma unroll
            for (int ee = 0; ee < 4; ++ee) {
                int tj_a = 8 * hi + 2 * ee, tj_b = tj_a + 1;
                float va = (tj_a <= 8) ? kern[o * 1296 + ti * 9 + tj_a] : 0.f;
                float vb = (tj_b <= 8) ? kern[o * 1296 + ti * 9 + tj_b] : 0.f;
                pk[ee] = f2bf(va) | (f2bf(vb) << 16);
            }
            Bf[ti] = __builtin_bit_cast(short8, (uint4v){pk[0], pk[1], pk[2], pk[3]});
        }
    }

    __syncthreads();   // staging barrier

    float16v acc[4];
#pragma unroll
    for (int pp = 0; pp < 4; ++pp)
#pragma unroll
        for (int e = 0; e < 16; ++e) acc[pp][e] = 0.f;
    float16v zero16;
#pragma unroll
    for (int e = 0; e < 16; ++e) zero16[e] = 0.f;

    // per-lane base: chunk ti of channel c at lb + c*CHB + (8-ti)*288
    const char* lb = (const char*)ldsb
                   + (240 - 16 * jm + 16 * hi) + (1 + rl) * 288
                   + cg * 8 * CHB;

    for (int c = 0; c < 8; ++c) {
        float16v D[4];
#pragma unroll
        for (int ti = 0; ti < 9; ++ti) {
            const char* p = lb + (8 - ti) * 288;
            uint4v w0 = *(const uint4v*)p;
            uint4v w1 = *(const uint4v*)(p + 16);
            unsigned int wnd[8] = {w0.x, w0.y, w0.z, w0.w,
                                   w1.x, w1.y, w1.z, w1.w};
            short8 f0, f1, f2, f3;
            if (ph == 0) {   // p=0..3 -> frag byte offsets 14,12,10,8
                f0 = FRAG_ODD(3);  f1 = FRAG_EVEN(3);
                f2 = FRAG_ODD(2);  f3 = FRAG_EVEN(2);
            } else {         // p=4..7 -> frag byte offsets 6,4,2,0
                f0 = FRAG_ODD(1);  f1 = FRAG_EVEN(1);
                f2 = FRAG_ODD(0);  f3 = FRAG_EVEN(0);
            }
            D[0] = __builtin_amdgcn_mfma_f32_32x32x16_bf16(f0, Bf[ti], ti ? D[0] : zero16, 0, 0, 0);
            D[1] = __builtin_amdgcn_mfma_f32_32x32x16_bf16(f1, Bf[ti], ti ? D[1] : zero16, 0, 0, 0);
            D[2] = __builtin_amdgcn_mfma_f32_32x32x16_bf16(f2, Bf[ti], ti ? D[2] : zero16, 0, 0, 0);
            D[3] = __builtin_amdgcn_mfma_f32_32x32x16_bf16(f3, Bf[ti], ti ? D[3] : zero16, 0, 0, 0);
        }
#pragma unroll
        for (int pp = 0; pp < 4; ++pp)
#pragma unroll
            for (int e = 0; e < 16; ++e) acc[pp][e] += fabsf(D[pp][e]);
        lb += CHB;
    }

    // ---- cg-reduce + transpose via stride-129 LDS out-tile (R12 verbatim)
    __syncthreads();   // all x-tile reads done; safe to overwrite ldsb
    float* otile = (float*)ldsb;
    const int obase_l = (l & 31) * 129 + 32 * (l >> 5) + 4 * ph;
    if (cg == 1) {
#pragma unroll
        for (int pp = 0; pp < 4; ++pp)
#pragma unroll
            for (int reg = 0; reg < 16; ++reg)
                otile[obase_l + (reg >> 3) * 4128 + 8 * (reg & 3)
                      + 64 * ((reg >> 2) & 1) + pp] = acc[pp][reg];
    }
    __syncthreads();
    if (cg == 0) {
#pragma unroll
        for (int pp = 0; pp < 4; ++pp)
#pragma unroll
            for (int reg = 0; reg < 16; ++reg) {
                const int idx = obase_l + (reg >> 3) * 4128 + 8 * (reg & 3)
                              + 64 * ((reg >> 2) & 1) + pp;
                otile[idx] += acc[pp][reg];
            }
    }
    __syncthreads();

    // flush: pair = r*32+o (64 pairs), 4 threads/pair cover 128 floats
    {
        const int pair = tid >> 2;     // 0..63
        const int q    = tid & 3;      // 32-float quarter
        const int r    = pair >> 5;
        const int o    = pair & 31;
        const float* src = otile + pair * 129 + q * 32;
        float* dstg = out + ((((size_t)(b * 32 + o)) * 128 + (i0 + r)) << 7) + q * 32;
#pragma unroll
        for (int k4 = 0; k4 < 8; ++k4) {
            float4v v = (float4v){src[4 * k4], src[4 * k4 + 1],
                                  src[4 * k4 + 2], src[4 * k4 + 3]};
            *(float4v*)&dstg[4 * k4] = v;
        }
    }
}

extern "C" void kernel_launch(void* const* d_in, const int* in_sizes, int n_in,
                              void* d_out, int out_size, void* d_ws, size_t ws_size,
                              hipStream_t stream) {
    const float* x = (const float*)d_in[0];      // [8,16,128,128]
    const float* kern = (const float*)d_in[1];   // [32,16,9,9]
    float* out = (float*)d_out;                  // [8,32,128,128]
    hipLaunchKernelGGL(optical_conv_69698729279498, dim3(64, 8), dim3(256),
                       0, stream, x, kern, out);
}

// Round 14
// 94.149 us; speedup vs baseline: 1.0408x; 1.0408x over previous
//
#include <hip/hip_runtime.h>

// out[b,o,i,j] = sum_c | sum_{ti,tj<=8} K[o,0,ti,tj] * x[b,c,(i+5-ti)&127,(j+5-tj)&127] |
// B=8 C=16 H=W=128 O=32.
// R14 = R12 (best, 94.4us) + conflict-free epilogue flush.
//   32x32x16 MFMA im2col: chunk = tap-row ti (K=16, tj pad 9->16), 9 chunks,
//   8 phases via ph-wave split + alignbit extraction; A lane map keeps the
//   R9-verified byte layout; D map (m74/m101): col=lane&31,
//   row=(reg&3)+8*(reg>>2)+4*(lane>>5). cg-reduce + transpose via stride-129
//   LDS out-tile. Staging DMA + xr layout byte-identical to R8-R12.
//   FLUSH FIX (R13 counters: 1.57e6 bank conflicts): old mapping pair=tid>>2,
//   q=tid&3 put the 4 q-lanes of a pair on one bank-quad (q*32 = 0 mod 32
//   banks) -> 4-way conflict. New mapping pair=lane, q=wave: bank =
//   (l + 4k) mod 32, 2 lanes/bank = free.
//   Spill tell: WRITE_SIZE > 16384 KB. Correctness tell: absmax == 0.0625.

typedef __attribute__((ext_vector_type(8)))  short  short8;
typedef __attribute__((ext_vector_type(16))) float  float16v;
typedef __attribute__((ext_vector_type(4)))  float  float4v;
typedef __attribute__((ext_vector_type(4)))  unsigned int uint4v;

#define XR_ROWS 138                   // 128 + 9 replicated + 1 pad
#define XR_RDW  72                    // dwords per row (144 bf16 = 288 B)
#define XR_CH_DW (XR_ROWS * XR_RDW)   // 9936 dwords per channel
#define XR_CH_B  (XR_CH_DW * 4)       // 39744 B per channel
#define BPRE_OFF ((size_t)128 * XR_ROWS * 288)   // 5,087,232 B (16B aligned)
#define CHB 3168                      // LDS bytes per channel (11 rows x 288)

__device__ __forceinline__ unsigned int f2bf(float f) {
    union { float f; unsigned int u; } a; a.f = f;
    unsigned int u = a.u;
    u += 0x7fffu + ((u >> 16) & 1u);   // RNE
    return u >> 16;
}

#if __has_builtin(__builtin_amdgcn_alignbit)
#define ALIGN16(hi_, lo_) __builtin_amdgcn_alignbit((hi_), (lo_), 16)
#else
#define ALIGN16(hi_, lo_) \
    (unsigned int)((((unsigned long long)(hi_) << 32) | (lo_)) >> 16)
#endif

#define FRAG_EVEN(q_) __builtin_bit_cast(short8, (uint4v){                    \
        wnd[(q_)+0], wnd[(q_)+1], wnd[(q_)+2], wnd[(q_)+3]})
#define FRAG_ODD(q_)  __builtin_bit_cast(short8, (uint4v){                    \
        ALIGN16(wnd[(q_)+1], wnd[(q_)+0]),                                    \
        ALIGN16(wnd[(q_)+2], wnd[(q_)+1]),                                    \
        ALIGN16(wnd[(q_)+3], wnd[(q_)+2]),                                    \
        ALIGN16(wnd[(q_)+4], wnd[(q_)+3])})

__device__ __forceinline__ void gload_lds16(const void* g, void* l) {
    __builtin_amdgcn_global_load_lds(
        (const __attribute__((address_space(1))) unsigned int*)g,
        (__attribute__((address_space(3))) unsigned int*)l, 16, 0, 0);
}

// ---- prep: xr = column-reversed bf16 x with replicated wrap rows (divide-
//      light grid mapping); bpre = per-lane 32x32x16 B-frags (block x=39,y=0).
__global__ __launch_bounds__(256)
void optical_prep_69698729279498(const float* __restrict__ x,
                                 const float* __restrict__ kern,
                                 unsigned int* __restrict__ xr,
                                 uint4v* __restrict__ bpre) {
    const int t = blockIdx.x * 256 + threadIdx.x;
    const int bc = blockIdx.y;
    const int rem = t - 9984;          // bx==39 => t in [9984,10240)
    if (t < XR_CH_DW) {
        int r   = t / 72;              // magic-mul division
        int ccd = t - r * 72;
        int cc  = 2 * ccd;
        const float* xp = x + (bc << 14) + ((r & 127) << 7);
        float v0 = xp[(132 - cc) & 127];
        float v1 = xp[(131 - cc) & 127];
        xr[(size_t)bc * XR_CH_DW + t] = f2bf(v0) | (f2bf(v1) << 16);
    } else if (bc == 0 && rem >= 0 && rem < 64) {
        const int l  = rem;
        const int o  = l & 31;
        const int hi = l >> 5;
        for (int ti = 0; ti < 9; ++ti) {
            unsigned int pk[4];
#pragma unroll
            for (int ee = 0; ee < 4; ++ee) {
                int tj_a = 8 * hi + 2 * ee, tj_b = tj_a + 1;
                float va = (tj_a <= 8) ? kern[o * 1296 + ti * 9 + tj_a] : 0.f;
                float vb = (tj_b <= 8) ? kern[o * 1296 + ti * 9 + tj_b] : 0.f;
                pk[ee] = f2bf(va) | (f2bf(vb) << 16);
            }
            bpre[ti * 64 + l] = (uint4v){pk[0], pk[1], pk[2], pk[3]};
        }
    }
}

// ---- main
__global__ __launch_bounds__(256, 2)
void optical_conv_69698729279498(const unsigned int* __restrict__ xr,
                                 const uint4v* __restrict__ bpre,
                                 float* __restrict__ out) {
    __shared__ __align__(16) unsigned short ldsb[16 * (CHB / 2)];  // 50688 B

    const int tid = threadIdx.x;
    const int l   = tid & 63;
    const int w   = tid >> 6;        // wave 0..3
    const int ph  = w & 1;           // phase half: p = 4*ph + pp
    const int cg  = w >> 1;          // channel group 0..1
    const int i0  = blockIdx.x * 2;  // first output row of tile
    const int b   = blockIdx.y;      // batch 0..7

    const int jm  = l & 15;          // A m: m = 16*rl + jm
    const int rl  = (l >> 4) & 1;    // row within 2-row tile (per-lane!)
    const int hi  = l >> 5;          // k half: tj = 8*hi + j

    // ---- staging: wave w DMAs channels 4w..4w+3 (verified R8-R12)
    const int wstart = (i0 >= 4) ? (i0 - 4) : (i0 + 124);
    const char* xr8 = (const char*)xr;
#pragma unroll
    for (int cw = 0; cw < 4; ++cw) {
        const int ch = 4 * w + cw;
        const char* src = xr8 + ((size_t)((b * 16 + ch) * XR_ROWS + wstart)) * 288;
        char* dst = (char*)ldsb + ch * CHB;
        gload_lds16(src + 0 * 1024 + l * 16, dst + 0 * 1024);
        gload_lds16(src + 1 * 1024 + l * 16, dst + 1 * 1024);
        gload_lds16(src + 2 * 1024 + l * 16, dst + 2 * 1024);
        if (l < 6)   // tail: 3168 - 3072 = 96 B
            gload_lds16(src + 3072 + l * 16, dst + 3072);
    }

    // ---- B fragments: 9 coalesced dwordx4 loads (all 32 o per lane)
    short8 Bf[9];
#pragma unroll
    for (int ti = 0; ti < 9; ++ti)
        Bf[ti] = __builtin_bit_cast(short8, bpre[ti * 64 + l]);

    __syncthreads();   // staging barrier (drains global_load_lds queue)

    float16v acc[4];
#pragma unroll
    for (int pp = 0; pp < 4; ++pp)
#pragma unroll
        for (int e = 0; e < 16; ++e) acc[pp][e] = 0.f;
    float16v zero16;
#pragma unroll
    for (int e = 0; e < 16; ++e) zero16[e] = 0.f;

    // per-lane base: chunk ti of channel c at lb + c*CHB + (8-ti)*288
    const char* lb = (const char*)ldsb
                   + (240 - 16 * jm + 16 * hi) + (1 + rl) * 288
                   + cg * 8 * CHB;

    for (int c = 0; c < 8; ++c) {
        float16v D[4];
#pragma unroll
        for (int ti = 0; ti < 9; ++ti) {
            const char* p = lb + (8 - ti) * 288;
            uint4v w0 = *(const uint4v*)p;
            uint4v w1 = *(const uint4v*)(p + 16);
            unsigned int wnd[8] = {w0.x, w0.y, w0.z, w0.w,
                                   w1.x, w1.y, w1.z, w1.w};
            short8 f0, f1, f2, f3;
            if (ph == 0) {   // p=0..3 -> frag byte offsets 14,12,10,8
                f0 = FRAG_ODD(3);  f1 = FRAG_EVEN(3);
                f2 = FRAG_ODD(2);  f3 = FRAG_EVEN(2);
            } else {         // p=4..7 -> frag byte offsets 6,4,2,0
                f0 = FRAG_ODD(1);  f1 = FRAG_EVEN(1);
                f2 = FRAG_ODD(0);  f3 = FRAG_EVEN(0);
            }
            D[0] = __builtin_amdgcn_mfma_f32_32x32x16_bf16(f0, Bf[ti], ti ? D[0] : zero16, 0, 0, 0);
            D[1] = __builtin_amdgcn_mfma_f32_32x32x16_bf16(f1, Bf[ti], ti ? D[1] : zero16, 0, 0, 0);
            D[2] = __builtin_amdgcn_mfma_f32_32x32x16_bf16(f2, Bf[ti], ti ? D[2] : zero16, 0, 0, 0);
            D[3] = __builtin_amdgcn_mfma_f32_32x32x16_bf16(f3, Bf[ti], ti ? D[3] : zero16, 0, 0, 0);
        }
#pragma unroll
        for (int pp = 0; pp < 4; ++pp)
#pragma unroll
            for (int e = 0; e < 16; ++e) acc[pp][e] += fabsf(D[pp][e]);
        lb += CHB;
    }

    // ---- cg-reduce + transpose via stride-129 LDS out-tile (conflict-free:
    //      129 = 1 mod 32), then coalesced float4 flush.
    // idx(lane,reg,p) = (r*32+o)*129 + 8*jm' + p,  r=reg>>3, o=l&31,
    // jm' = (reg&3) + 8*((reg>>2)&1) + 4*(l>>5)  [verified D map m74/m101]
    __syncthreads();   // all x-tile reads done; safe to overwrite ldsb
    float* otile = (float*)ldsb;
    const int obase_l = (l & 31) * 129 + 32 * (l >> 5) + 4 * ph;
    if (cg == 1) {
#pragma unroll
        for (int pp = 0; pp < 4; ++pp)
#pragma unroll
            for (int reg = 0; reg < 16; ++reg)
                otile[obase_l + (reg >> 3) * 4128 + 8 * (reg & 3)
                      + 64 * ((reg >> 2) & 1) + pp] = acc[pp][reg];
    }
    __syncthreads();
    if (cg == 0) {
#pragma unroll
        for (int pp = 0; pp < 4; ++pp)
#pragma unroll
            for (int reg = 0; reg < 16; ++reg) {
                const int idx = obase_l + (reg >> 3) * 4128 + 8 * (reg & 3)
                              + 64 * ((reg >> 2) & 1) + pp;
                otile[idx] += acc[pp][reg];
            }
    }
    __syncthreads();

    // flush (R14 fix): pair = lane (0..63), quarter = wave. Bank =
    // (l + 4k4) mod 32 -> 2 lanes/bank (free). Coalesced float4 global stores.
    {
        const int pair = l;            // r*32 + o
        const int q    = w;            // 32-float quarter
        const int r    = pair >> 5;
        const int o    = pair & 31;
        const float* src = otile + pair * 129 + q * 32;
        float* dstg = out + ((((size_t)(b * 32 + o)) * 128 + (i0 + r)) << 7) + q * 32;
#pragma unroll
        for (int k4 = 0; k4 < 8; ++k4) {
            float4v v = (float4v){src[4 * k4], src[4 * k4 + 1],
                                  src[4 * k4 + 2], src[4 * k4 + 3]};
            *(float4v*)&dstg[4 * k4] = v;
        }
    }
}

extern "C" void kernel_launch(void* const* d_in, const int* in_sizes, int n_in,
                              void* d_out, int out_size, void* d_ws, size_t ws_size,
                              hipStream_t stream) {
    const float* x = (const float*)d_in[0];      // [8,16,128,128]
    const float* kern = (const float*)d_in[1];   // [32,16,9,9]
    float* out = (float*)d_out;                  // [8,32,128,128]
    unsigned int* xr = (unsigned int*)d_ws;                        // 5.09 MB
    uint4v* bpre = (uint4v*)((char*)d_ws + BPRE_OFF);              // +9.2 KB

    hipLaunchKernelGGL(optical_prep_69698729279498, dim3(40, 128),
                       dim3(256), 0, stream, x, kern, xr, bpre);
    hipLaunchKernelGGL(optical_conv_69698729279498, dim3(64, 8), dim3(256),
                       0, stream, xr, bpre, out);
}